// Round 6
// baseline (5930.716 us; speedup 1.0000x reference)
//
#include <hip/hip_runtime.h>
#include <math.h>

#define B_ 32
#define T_ 128
#define D_ 512
#define U_ 512
#define G_ 2048   // 4U
#define NGRP 8    // batch groups
#define GB 4      // batches per group
#define WPG 32    // workgroups per group
#define NT 512    // threads per WG
#define GK 512    // K dim of precompute GEMMs

typedef unsigned long long u64;

__device__ __forceinline__ unsigned short f2bf(float v) {
  unsigned u = __float_as_uint(v);
  return (unsigned short)((u + 0x7FFFu + ((u >> 16) & 1u)) >> 16);
}
__device__ __forceinline__ float bf2f(unsigned short u) {
  return __uint_as_float(((unsigned)u) << 16);
}

// Tagged-pair (value, epoch) through the MALL: 8B atomic => value+tag are
// always mutually consistent; no fences, no barriers needed.
__device__ __forceinline__ void pair_store(u64* p, float v, unsigned tag) {
  u64 pk = ((u64)tag << 32) | (u64)__float_as_uint(v);
  __hip_atomic_store(p, pk, __ATOMIC_RELAXED, __HIP_MEMORY_SCOPE_AGENT);
}
__device__ __forceinline__ u64 pair_load(const u64* p) {
  return __hip_atomic_load(p, __ATOMIC_RELAXED, __HIP_MEMORY_SCOPE_AGENT);
}

// ---------------------------------------------------------------------------
// Precompute GEMM: C[M,N] = A[M,512] @ W[512,N] + bias  (bias may be null)
// MODE 1: bf16 row-major; MODE 2: fp32 (B,U,T)-transposed
// ---------------------------------------------------------------------------
template <int MODE>
__global__ __launch_bounds__(256) void gemm_bias_t(const float* __restrict__ A,
                                                   const float* __restrict__ W,
                                                   const float* __restrict__ bias,
                                                   void* __restrict__ Cout, int N) {
  __shared__ float As[16][68];
  __shared__ float Ws[16][64];
  const int tid = threadIdx.x;
  const int rowbase = blockIdx.y * 64;
  const int colbase = blockIdx.x * 64;
  const int ty = tid >> 4, tx = tid & 15;
  const int ar = tid >> 2, ak = (tid & 3) << 2;
  const int wk = tid >> 4, wc = (tid & 15) << 2;
  float acc[4][4] = {{0.f, 0.f, 0.f, 0.f}};
  for (int k0 = 0; k0 < GK; k0 += 16) {
    float4 av = *(const float4*)(A + (size_t)(rowbase + ar) * GK + k0 + ak);
    float4 wv = *(const float4*)(W + (size_t)(k0 + wk) * N + colbase + wc);
    __syncthreads();
    As[ak + 0][ar] = av.x;
    As[ak + 1][ar] = av.y;
    As[ak + 2][ar] = av.z;
    As[ak + 3][ar] = av.w;
    *(float4*)(&Ws[wk][wc]) = wv;
    __syncthreads();
#pragma unroll
    for (int kk = 0; kk < 16; ++kk) {
      float4 a = *(const float4*)(&As[kk][ty << 2]);
      float4 wv2 = *(const float4*)(&Ws[kk][tx << 2]);
      float a4[4] = {a.x, a.y, a.z, a.w};
      float w4[4] = {wv2.x, wv2.y, wv2.z, wv2.w};
#pragma unroll
      for (int i = 0; i < 4; ++i)
#pragma unroll
        for (int jj = 0; jj < 4; ++jj) acc[i][jj] += a4[i] * w4[jj];
    }
  }
  float4 bv = bias ? *(const float4*)(bias + colbase + (tx << 2))
                   : make_float4(0.f, 0.f, 0.f, 0.f);
#pragma unroll
  for (int i = 0; i < 4; ++i) {
    const int row = rowbase + (ty << 2) + i;
    float o[4] = {acc[i][0] + bv.x, acc[i][1] + bv.y, acc[i][2] + bv.z,
                  acc[i][3] + bv.w};
    if (MODE == 1) {
      ushort4 ob;
      ob.x = f2bf(o[0]); ob.y = f2bf(o[1]); ob.z = f2bf(o[2]); ob.w = f2bf(o[3]);
      *(ushort4*)((unsigned short*)Cout + (size_t)row * N + colbase + (tx << 2)) = ob;
    } else {
      const int b = row >> 7, tt = row & 127;
#pragma unroll
      for (int jj = 0; jj < 4; ++jj) {
        int u = colbase + (tx << 2) + jj;
        ((float*)Cout)[((size_t)b * U_ + u) * T_ + tt] = o[jj];
      }
    }
  }
}

__device__ __forceinline__ float tanh_fast(float x) {
  return 1.f - 2.f / (__expf(2.f * x) + 1.f);
}

// ---------------------------------------------------------------------------
// Barrier-free weight-stationary recurrence. 8 groups x 32 WGs x 512 thr.
// All cross-WG state (score partials sp2, hidden state h2) flows as tagged
// (value,epoch) pairs; consumers spin on tag equality. Epochs cannot skip:
// sp(e+1) writes require h(e) observed, h(e) published only after sp(e)
// consumed (and symmetrically), so equality-polling is exact and the 0xAA
// workspace poison (tag 0xAAAAAAAA) never matches a real epoch in [1,128].
// ---------------------------------------------------------------------------
__global__ __launch_bounds__(NT) void attlstm_rec(
    const unsigned short* __restrict__ xk,  // (B,T,4U) bf16
    const unsigned short* __restrict__ xA,  // (B,T,4U) bf16
    const float* __restrict__ attxT,        // (B,U,T) fp32
    const float* __restrict__ Rk,           // (U,4U)
    const float* __restrict__ Um,           // (U,U)
    const float* __restrict__ V,            // (U)
    u64* __restrict__ h2,                   // (B,U) tagged pairs
    u64* __restrict__ sp2,                  // (NGRP,GB,T,WPG) tagged pairs
    float* __restrict__ out) {              // (B,T,U)
  const int bg = blockIdx.x & 7;
  const int w = blockIdx.x >> 3;
  const int tid = threadIdx.x;
  const int u0 = w * 16;
  const int tk = tid >> 4;  // 0..31 (K-chunk of 16)
  const int tc = tid & 15;  // col-quad id
  const int gcol = (tc >> 2) * U_ + u0 + (tc & 3) * 4;
  const int wv = tid >> 6;
  const int lane = tid & 63;
  const int bS = tid >> 7;
  const int tS = tid & 127;
  const int rb = tid >> 6;  // reducer role (tid<256)
  const int rc = tid & 63;
  const int rtc = rc >> 2, rcomp = rc & 3;
  const int rg = rtc >> 2;
  const int rui = ((rtc & 3) << 2) | rcomp;
  const int rcol = rg * U_ + u0 + rui;

  __shared__ float attx_l[16 * GB * T_];  // 32 KB
  __shared__ float h_s[GB][U_];           // 8 KB
  __shared__ float4 red2[8][GB][17];
  __shared__ float hUred[8][GB][17];
  __shared__ float sc_s[GB][T_];
  __shared__ float hU_s[GB][16];
  __shared__ float act_s[GB][64];
  __shared__ float c_s[GB][16];
  __shared__ float lsum_s[8];
  __shared__ float Vs_l[16];

  float4 Rw[16];
  float Uw[16];
#pragma unroll
  for (int i = 0; i < 16; ++i)
    Rw[i] = *(const float4*)(Rk + (size_t)(tk * 16 + i) * G_ + gcol);
#pragma unroll
  for (int i = 0; i < 16; ++i)
    Uw[i] = Um[(size_t)(tk * 16 + i) * U_ + u0 + tc];

  for (int idx = tid; idx < 16 * GB * T_; idx += NT) {
    int uc = idx >> 9;
    int b = (idx >> 7) & 3;
    int tt = idx & 127;
    attx_l[idx] = attxT[((size_t)(bg * GB + b) * U_ + u0 + uc) * T_ + tt];
  }
  for (int i = tid; i < GB * U_; i += NT) ((float*)h_s)[i] = 0.f;
  if (tid < GB * 16) ((float*)c_s)[tid] = 0.f;
  if (tid < 16) Vs_l[tid] = V[u0 + tid];
  u64* h2g = h2 + (size_t)bg * GB * U_;
  u64* sp2g = sp2 + (size_t)bg * GB * T_ * WPG;
  __syncthreads();

  for (int t = 0; t < T_; ++t) {
    const unsigned tag = t + 1;
    // ---- h(t) ingest: poll tagged pairs (replaces barrier B2) ----
    if (t > 0) {
      const u64* hp = h2g + tid * 4;
      u64 v0 = pair_load(hp + 0);
      u64 v1 = pair_load(hp + 1);
      u64 v2 = pair_load(hp + 2);
      u64 v3 = pair_load(hp + 3);
      float vals[4];
      unsigned stale = 0;
      if ((unsigned)(v0 >> 32) == (unsigned)t) vals[0] = __uint_as_float((unsigned)v0); else stale |= 1;
      if ((unsigned)(v1 >> 32) == (unsigned)t) vals[1] = __uint_as_float((unsigned)v1); else stale |= 2;
      if ((unsigned)(v2 >> 32) == (unsigned)t) vals[2] = __uint_as_float((unsigned)v2); else stale |= 4;
      if ((unsigned)(v3 >> 32) == (unsigned)t) vals[3] = __uint_as_float((unsigned)v3); else stale |= 8;
      while (stale) {
        unsigned m = stale;
        do {
          int k = __builtin_ctz(m);
          m &= m - 1;
          u64 v = pair_load(hp + k);
          if ((unsigned)(v >> 32) == (unsigned)t) {
            vals[k] = __uint_as_float((unsigned)v);
            stale &= ~(1u << k);
          }
        } while (m);
      }
      *(float4*)&((float*)h_s)[tid * 4] =
          make_float4(vals[0], vals[1], vals[2], vals[3]);
    }
    __syncthreads();

    float xkv = 0.f;
    if (tid < 256)
      xkv = bf2f(xk[((size_t)(bg * GB + rb) * T_ + t) * G_ + rcol]);

    // ===== P1: h@Rk partial + h@Um partial (register-stationary)
    float4 accR[GB];
    float hUa[GB];
#pragma unroll
    for (int b = 0; b < GB; ++b) {
      float4 a = make_float4(0.f, 0.f, 0.f, 0.f);
      float hu = 0.f;
      const float* hp = &h_s[b][tk * 16];
#pragma unroll
      for (int i = 0; i < 16; ++i) {
        float hv = hp[i];
        a.x += hv * Rw[i].x;
        a.y += hv * Rw[i].y;
        a.z += hv * Rw[i].z;
        a.w += hv * Rw[i].w;
        hu += hv * Uw[i];
      }
      accR[b] = a;
      hUa[b] = hu;
    }
#pragma unroll
    for (int b = 0; b < GB; ++b) {
      float hu = hUa[b];
      hu += __shfl_down(hu, 32);
      hu += __shfl_down(hu, 16);
      if (lane < 16) hUred[wv][b][lane] = hu;
    }
    __syncthreads();
    if (tid < 64) {
      int b = tid >> 4, u = tid & 15;
      float s = 0.f;
#pragma unroll
      for (int k = 0; k < 8; ++k) s += hUred[k][b][u];
      hU_s[b][u] = s;
    }
    __syncthreads();
    {  // score partials over own 16-u slice -> tagged pair store
      float s = 0.f;
      const float* ax = &attx_l[bS * T_ + tS];
#pragma unroll
      for (int uc = 0; uc < 16; ++uc) {
        float e = tanh_fast(ax[uc * (GB * T_)] + hU_s[bS][uc]);
        s += e * Vs_l[uc];
      }
      pair_store(&sp2g[((size_t)bS * T_ + tS) * WPG + w], s, tag);
    }

    // ===== P2: poll sp pairs, softmax (no max pass: |score|<~20), fold
    {
      const u64* spp = sp2g + ((size_t)bS * T_ + tS) * WPG;
      float s = 0.f;
      unsigned stale = 0;
#pragma unroll
      for (int ww = 0; ww < WPG; ++ww) {
        u64 v = pair_load(spp + ww);
        bool ok = ((unsigned)(v >> 32) == tag);
        s += ok ? __uint_as_float((unsigned)v) : 0.f;
        stale |= ok ? 0u : (1u << ww);
      }
      while (stale) {
        unsigned m = stale;
        do {
          int ww = __builtin_ctz(m);
          m &= m - 1;
          u64 v = pair_load(spp + ww);
          if ((unsigned)(v >> 32) == tag) {
            s += __uint_as_float((unsigned)v);
            stale &= ~(1u << ww);
          }
        } while (m);
      }
      float e = __expf(s);  // scores bounded by ||V||_1 ~ 20: fp32-safe
      sc_s[bS][tS] = e;
      float ls = e;  // fold l-sum into wave-level reduce (lanes share bS)
      for (int o = 32; o > 0; o >>= 1) ls += __shfl_down(ls, o);
      if (lane == 0) lsum_s[wv] = ls;
    }
    __syncthreads();
#pragma unroll
    for (int b = 0; b < GB; ++b) {
      const unsigned short* xap =
          xA + ((size_t)(bg * GB + b) * T_ + tk * 4) * G_ + gcol;
      float4 az = make_float4(0.f, 0.f, 0.f, 0.f);
#pragma unroll
      for (int i = 0; i < 4; ++i) {
        ushort4 xv = *(const ushort4*)(xap + (size_t)i * G_);
        float al = sc_s[b][tk * 4 + i];
        az.x += al * bf2f(xv.x);
        az.y += al * bf2f(xv.y);
        az.z += al * bf2f(xv.z);
        az.w += al * bf2f(xv.w);
      }
      float il = 1.f / (lsum_s[2 * b] + lsum_s[2 * b + 1]);
      float4 comb;
      comb.x = accR[b].x + il * az.x;
      comb.y = accR[b].y + il * az.y;
      comb.z = accR[b].z + il * az.z;
      comb.w = accR[b].w + il * az.w;
      comb.x += __shfl_down(comb.x, 32);
      comb.y += __shfl_down(comb.y, 32);
      comb.z += __shfl_down(comb.z, 32);
      comb.w += __shfl_down(comb.w, 32);
      comb.x += __shfl_down(comb.x, 16);
      comb.y += __shfl_down(comb.y, 16);
      comb.z += __shfl_down(comb.z, 16);
      comb.w += __shfl_down(comb.w, 16);
      if (lane < 16) red2[wv][b][lane] = comb;
    }
    __syncthreads();
    if (tid < 256) {
      float gsum = xkv;
      const float* r2 = (const float*)red2;
#pragma unroll
      for (int k = 0; k < 8; ++k)
        gsum += r2[(((size_t)(k * GB + rb) * 17) + rtc) * 4 + rcomp];
      float gv = (rg == 2) ? tanh_fast(gsum)
                           : fminf(fmaxf(0.2f * gsum + 0.5f, 0.f), 1.f);
      act_s[rb][rg * 16 + rui] = gv;
    }
    __syncthreads();
    if (tid < 64) {
      int b = tid >> 4, ui = tid & 15;
      float i_ = act_s[b][ui];
      float f_ = act_s[b][16 + ui];
      float g_ = act_s[b][32 + ui];
      float o_ = act_s[b][48 + ui];
      float cn = f_ * c_s[b][ui] + i_ * g_;
      c_s[b][ui] = cn;
      float hn = o_ * tanh_fast(cn);
      int gb = bg * GB + b;
      pair_store(&h2g[(size_t)b * U_ + u0 + ui], hn, tag);
      out[((size_t)gb * T_ + t) * U_ + u0 + ui] = hn;
    }
    // no barrier: next iteration's h poll synchronizes
  }
}

// ---------------------------------------------------------------------------
extern "C" void kernel_launch(void* const* d_in, const int* in_sizes, int n_in,
                              void* d_out, int out_size, void* d_ws,
                              size_t ws_size, hipStream_t stream) {
  (void)in_sizes;
  (void)n_in;
  (void)out_size;
  (void)ws_size;
  const float* x = (const float*)d_in[0];
  const float* Wk = (const float*)d_in[1];
  const float* Rk = (const float*)d_in[2];
  const float* Ak = (const float*)d_in[3];
  const float* Wa = (const float*)d_in[4];
  const float* Ua = (const float*)d_in[5];
  const float* Va = (const float*)d_in[6];
  const float* bias = (const float*)d_in[7];
  const float* ba = (const float*)d_in[8];
  float* out = (float*)d_out;

  char* ws = (char*)d_ws;
  unsigned short* xk_b = (unsigned short*)(ws);            // 16 MiB
  unsigned short* xA_b = (unsigned short*)(ws + 16777216); // 16 MiB
  float* attxT = (float*)(ws + 33554432);                  // 8 MiB
  u64* h2 = (u64*)(ws + 41943040);                         // 128 KiB
  u64* sp2 = (u64*)(ws + 42074112);                        // 1 MiB

  gemm_bias_t<1><<<dim3(G_ / 64, (B_ * T_) / 64), 256, 0, stream>>>(
      x, Wk, bias, xk_b, G_);
  gemm_bias_t<1><<<dim3(G_ / 64, (B_ * T_) / 64), 256, 0, stream>>>(
      x, Ak, nullptr, xA_b, G_);
  gemm_bias_t<2><<<dim3(U_ / 64, (B_ * T_) / 64), 256, 0, stream>>>(
      x, Wa, ba, attxT, U_);

  attlstm_rec<<<dim3(NGRP * WPG), dim3(NT), 0, stream>>>(
      xk_b, xA_b, attxT, Rk, Ua, Va, h2, sp2, out);
}

// Round 7
// 1996.989 us; speedup vs baseline: 2.9698x; 2.9698x over previous
//
#include <hip/hip_runtime.h>
#include <math.h>

#define B_ 32
#define T_ 128
#define D_ 512
#define U_ 512
#define G_ 2048   // 4U
#define NGRP 8    // batch groups
#define GB 4      // batches per group
#define WPG 32    // workgroups per group
#define NT 512    // threads per WG
#define GK 512    // K dim of precompute GEMMs

__device__ __forceinline__ unsigned short f2bf(float v) {
  unsigned u = __float_as_uint(v);
  return (unsigned short)((u + 0x7FFFu + ((u >> 16) & 1u)) >> 16);
}
__device__ __forceinline__ float bf2f(unsigned short u) {
  return __uint_as_float(((unsigned)u) << 16);
}

// 4B cache-bypassing store (write-through to the device coherence point).
__device__ __forceinline__ void dev_store(float* p, float v) {
  __hip_atomic_store(p, v, __ATOMIC_RELAXED, __HIP_MEMORY_SCOPE_AGENT);
}

// 32 contiguous floats as 8 pipelined dwordx4 bypass loads + ONE waitcnt.
// sc0 sc1 => skip L1/L2, read the device coherence point (fresh after the
// group barrier). Early-clobber outputs so none alias the address pair.
__device__ __forceinline__ void gather32(const float* p, float4& a0, float4& a1,
                                         float4& a2, float4& a3, float4& a4,
                                         float4& a5, float4& a6, float4& a7) {
  asm volatile(
      "global_load_dwordx4 %0, %8, off sc0 sc1\n\t"
      "global_load_dwordx4 %1, %8, off offset:16 sc0 sc1\n\t"
      "global_load_dwordx4 %2, %8, off offset:32 sc0 sc1\n\t"
      "global_load_dwordx4 %3, %8, off offset:48 sc0 sc1\n\t"
      "global_load_dwordx4 %4, %8, off offset:64 sc0 sc1\n\t"
      "global_load_dwordx4 %5, %8, off offset:80 sc0 sc1\n\t"
      "global_load_dwordx4 %6, %8, off offset:96 sc0 sc1\n\t"
      "global_load_dwordx4 %7, %8, off offset:112 sc0 sc1\n\t"
      "s_waitcnt vmcnt(0)"
      : "=&v"(a0), "=&v"(a1), "=&v"(a2), "=&v"(a3), "=&v"(a4), "=&v"(a5),
        "=&v"(a6), "=&v"(a7)
      : "v"(p)
      : "memory");
}

__device__ __forceinline__ float4 load4_coh(const float* p) {
  float4 r;
  asm volatile(
      "global_load_dwordx4 %0, %1, off sc0 sc1\n\t"
      "s_waitcnt vmcnt(0)"
      : "=&v"(r)
      : "v"(p)
      : "memory");
  return r;
}

// ---------------------------------------------------------------------------
// Precompute GEMM: C[M,N] = A[M,512] @ W[512,N] + bias  (bias may be null)
// MODE 1: bf16 row-major; MODE 2: fp32 (B,U,T)-transposed
// ---------------------------------------------------------------------------
template <int MODE>
__global__ __launch_bounds__(256) void gemm_bias_t(const float* __restrict__ A,
                                                   const float* __restrict__ W,
                                                   const float* __restrict__ bias,
                                                   void* __restrict__ Cout, int N) {
  __shared__ float As[16][68];
  __shared__ float Ws[16][64];
  const int tid = threadIdx.x;
  const int rowbase = blockIdx.y * 64;
  const int colbase = blockIdx.x * 64;
  const int ty = tid >> 4, tx = tid & 15;
  const int ar = tid >> 2, ak = (tid & 3) << 2;
  const int wk = tid >> 4, wc = (tid & 15) << 2;
  float acc[4][4] = {{0.f, 0.f, 0.f, 0.f}};
  for (int k0 = 0; k0 < GK; k0 += 16) {
    float4 av = *(const float4*)(A + (size_t)(rowbase + ar) * GK + k0 + ak);
    float4 wv = *(const float4*)(W + (size_t)(k0 + wk) * N + colbase + wc);
    __syncthreads();
    As[ak + 0][ar] = av.x;
    As[ak + 1][ar] = av.y;
    As[ak + 2][ar] = av.z;
    As[ak + 3][ar] = av.w;
    *(float4*)(&Ws[wk][wc]) = wv;
    __syncthreads();
#pragma unroll
    for (int kk = 0; kk < 16; ++kk) {
      float4 a = *(const float4*)(&As[kk][ty << 2]);
      float4 wv2 = *(const float4*)(&Ws[kk][tx << 2]);
      float a4[4] = {a.x, a.y, a.z, a.w};
      float w4[4] = {wv2.x, wv2.y, wv2.z, wv2.w};
#pragma unroll
      for (int i = 0; i < 4; ++i)
#pragma unroll
        for (int jj = 0; jj < 4; ++jj) acc[i][jj] += a4[i] * w4[jj];
    }
  }
  float4 bv = bias ? *(const float4*)(bias + colbase + (tx << 2))
                   : make_float4(0.f, 0.f, 0.f, 0.f);
#pragma unroll
  for (int i = 0; i < 4; ++i) {
    const int row = rowbase + (ty << 2) + i;
    float o[4] = {acc[i][0] + bv.x, acc[i][1] + bv.y, acc[i][2] + bv.z,
                  acc[i][3] + bv.w};
    if (MODE == 1) {
      ushort4 ob;
      ob.x = f2bf(o[0]); ob.y = f2bf(o[1]); ob.z = f2bf(o[2]); ob.w = f2bf(o[3]);
      *(ushort4*)((unsigned short*)Cout + (size_t)row * N + colbase + (tx << 2)) = ob;
    } else {
      const int b = row >> 7, tt = row & 127;
#pragma unroll
      for (int jj = 0; jj < 4; ++jj) {
        int u = colbase + (tx << 2) + jj;
        ((float*)Cout)[((size_t)b * U_ + u) * T_ + tt] = o[jj];
      }
    }
  }
}

__device__ __forceinline__ float tanh_fast(float x) {
  return 1.f - 2.f / (__expf(2.f * x) + 1.f);
}

// RMW-free group barrier (R5-validated): own-slot store + 64-lane ballot poll.
__device__ __forceinline__ void grp_barrier(unsigned* slots, int w,
                                            unsigned epoch) {
  __syncthreads();  // drains vmcnt(0): all dev_stores at the coherence point
  if (threadIdx.x == 0)
    __hip_atomic_store(&slots[w], epoch, __ATOMIC_RELAXED,
                       __HIP_MEMORY_SCOPE_AGENT);
  if (threadIdx.x < 64) {
    bool done = false;
    do {
      unsigned v = (threadIdx.x < WPG)
                       ? __hip_atomic_load(&slots[threadIdx.x], __ATOMIC_RELAXED,
                                           __HIP_MEMORY_SCOPE_AGENT)
                       : epoch;
      done = __all(v >= epoch);
    } while (!done);
  }
  __syncthreads();
}

// ---------------------------------------------------------------------------
// Weight-stationary recurrence. 8 groups x 32 WGs x 512 threads.
// sp layout (b,t,w): a thread's 32 partials are one 128B block -> wide
// pipelined bypass gather. h exchange: one dwordx4/thread. No softmax max
// pass (scores bounded by ||V||_1 ~ 20). 2 barriers/step.
// ---------------------------------------------------------------------------
__global__ __launch_bounds__(NT) void attlstm_rec(
    const unsigned short* __restrict__ xk,  // (B,T,4U) bf16
    const unsigned short* __restrict__ xA,  // (B,T,4U) bf16
    const float* __restrict__ attxT,        // (B,U,T) fp32
    const float* __restrict__ Rk,           // (U,4U)
    const float* __restrict__ Um,           // (U,U)
    const float* __restrict__ V,            // (U)
    float* __restrict__ h_pub,              // (NGRP,GB,U)
    float* __restrict__ sp_g,               // (NGRP,GB,T,WPG)
    unsigned* __restrict__ bars,            // (NGRP,64)
    float* __restrict__ out) {              // (B,T,U)
  const int bg = blockIdx.x & 7;
  const int w = blockIdx.x >> 3;
  const int tid = threadIdx.x;
  const int u0 = w * 16;
  const int tk = tid >> 4;  // 0..31 (K-chunk of 16)
  const int tc = tid & 15;  // col-quad id
  const int gcol = (tc >> 2) * U_ + u0 + (tc & 3) * 4;
  const int wv = tid >> 6;
  const int lane = tid & 63;
  const int bS = tid >> 7;
  const int tS = tid & 127;
  const int rb = tid >> 6;  // reducer role (tid<256)
  const int rc = tid & 63;
  const int rtc = rc >> 2, rcomp = rc & 3;
  const int rg = rtc >> 2;
  const int rui = ((rtc & 3) << 2) | rcomp;
  const int rcol = rg * U_ + u0 + rui;

  __shared__ float attx_l[16 * GB * T_];  // 32 KB
  __shared__ float h_s[GB][U_];           // 8 KB
  __shared__ float4 red2[8][GB][17];
  __shared__ float hUred[8][GB][17];
  __shared__ float sc_s[GB][T_];
  __shared__ float hU_s[GB][16];
  __shared__ float act_s[GB][64];
  __shared__ float c_s[GB][16];
  __shared__ float lsum_s[8];
  __shared__ float Vs_l[16];

  float4 Rw[16];
  float Uw[16];
#pragma unroll
  for (int i = 0; i < 16; ++i)
    Rw[i] = *(const float4*)(Rk + (size_t)(tk * 16 + i) * G_ + gcol);
#pragma unroll
  for (int i = 0; i < 16; ++i)
    Uw[i] = Um[(size_t)(tk * 16 + i) * U_ + u0 + tc];

  for (int idx = tid; idx < 16 * GB * T_; idx += NT) {
    int uc = idx >> 9;
    int b = (idx >> 7) & 3;
    int tt = idx & 127;
    attx_l[idx] = attxT[((size_t)(bg * GB + b) * U_ + u0 + uc) * T_ + tt];
  }
  for (int i = tid; i < GB * U_; i += NT) ((float*)h_s)[i] = 0.f;
  if (tid < GB * 16) ((float*)c_s)[tid] = 0.f;
  if (tid < 16) Vs_l[tid] = V[u0 + tid];
  unsigned* slots = bars + bg * 64;
  unsigned epoch = 0;
  float* hpg = h_pub + (size_t)bg * GB * U_;
  float* spg = sp_g + (size_t)bg * GB * T_ * WPG;
  __syncthreads();

  for (int t = 0; t < T_; ++t) {
    float xkv = 0.f;
    if (tid < 256)
      xkv = bf2f(xk[((size_t)(bg * GB + rb) * T_ + t) * G_ + rcol]);

    // ===== P1: h@Rk partial + h@Um partial (register-stationary)
    float4 accR[GB];
    float hUa[GB];
#pragma unroll
    for (int b = 0; b < GB; ++b) {
      float4 a = make_float4(0.f, 0.f, 0.f, 0.f);
      float hu = 0.f;
      const float* hp = &h_s[b][tk * 16];
#pragma unroll
      for (int i = 0; i < 16; ++i) {
        float hv = hp[i];
        a.x += hv * Rw[i].x;
        a.y += hv * Rw[i].y;
        a.z += hv * Rw[i].z;
        a.w += hv * Rw[i].w;
        hu += hv * Uw[i];
      }
      accR[b] = a;
      hUa[b] = hu;
    }
#pragma unroll
    for (int b = 0; b < GB; ++b) {
      float hu = hUa[b];
      hu += __shfl_down(hu, 32);
      hu += __shfl_down(hu, 16);
      if (lane < 16) hUred[wv][b][lane] = hu;
    }
    __syncthreads();
    if (tid < 64) {
      int b = tid >> 4, u = tid & 15;
      float s = 0.f;
#pragma unroll
      for (int k = 0; k < 8; ++k) s += hUred[k][b][u];
      hU_s[b][u] = s;
    }
    __syncthreads();
    {  // score partials over own 16-u slice, all (b,t); layout (b,t,w)
      float s = 0.f;
      const float* ax = &attx_l[bS * T_ + tS];
#pragma unroll
      for (int uc = 0; uc < 16; ++uc) {
        float e = tanh_fast(ax[uc * (GB * T_)] + hU_s[bS][uc]);
        s += e * Vs_l[uc];
      }
      dev_store(&spg[((size_t)bS * T_ + tS) * WPG + w], s);
    }
    grp_barrier(slots, w, ++epoch);  // B1: all sp at coherence point

    // ===== P2: wide bypass gather -> softmax (no max pass) -> fold -> LSTM
    {
      const float* spp = spg + ((size_t)bS * T_ + tS) * WPG;
      float4 a0, a1, a2, a3, a4, a5, a6, a7;
      gather32(spp, a0, a1, a2, a3, a4, a5, a6, a7);
      float s = (((a0.x + a0.y) + (a0.z + a0.w)) + ((a1.x + a1.y) + (a1.z + a1.w))) +
                (((a2.x + a2.y) + (a2.z + a2.w)) + ((a3.x + a3.y) + (a3.z + a3.w))) +
                (((a4.x + a4.y) + (a4.z + a4.w)) + ((a5.x + a5.y) + (a5.z + a5.w))) +
                (((a6.x + a6.y) + (a6.z + a6.w)) + ((a7.x + a7.y) + (a7.z + a7.w)));
      float e = __expf(s);  // |s| <= ||V||_1 ~ 20: fp32-safe without shift
      sc_s[bS][tS] = e;
      float ls = e;  // lanes of this wave share bS
      for (int o = 32; o > 0; o >>= 1) ls += __shfl_down(ls, o);
      if (lane == 0) lsum_s[wv] = ls;
    }
    __syncthreads();
#pragma unroll
    for (int b = 0; b < GB; ++b) {
      const unsigned short* xap =
          xA + ((size_t)(bg * GB + b) * T_ + tk * 4) * G_ + gcol;
      float4 az = make_float4(0.f, 0.f, 0.f, 0.f);
#pragma unroll
      for (int i = 0; i < 4; ++i) {
        ushort4 xv = *(const ushort4*)(xap + (size_t)i * G_);
        float al = sc_s[b][tk * 4 + i];
        az.x += al * bf2f(xv.x);
        az.y += al * bf2f(xv.y);
        az.z += al * bf2f(xv.z);
        az.w += al * bf2f(xv.w);
      }
      float il = 1.f / (lsum_s[2 * b] + lsum_s[2 * b + 1]);
      float4 comb;
      comb.x = accR[b].x + il * az.x;
      comb.y = accR[b].y + il * az.y;
      comb.z = accR[b].z + il * az.z;
      comb.w = accR[b].w + il * az.w;
      comb.x += __shfl_down(comb.x, 32);
      comb.y += __shfl_down(comb.y, 32);
      comb.z += __shfl_down(comb.z, 32);
      comb.w += __shfl_down(comb.w, 32);
      comb.x += __shfl_down(comb.x, 16);
      comb.y += __shfl_down(comb.y, 16);
      comb.z += __shfl_down(comb.z, 16);
      comb.w += __shfl_down(comb.w, 16);
      if (lane < 16) red2[wv][b][lane] = comb;
    }
    __syncthreads();
    if (tid < 256) {
      float gsum = xkv;
      const float* r2 = (const float*)red2;
#pragma unroll
      for (int k = 0; k < 8; ++k)
        gsum += r2[(((size_t)(k * GB + rb) * 17) + rtc) * 4 + rcomp];
      float gv = (rg == 2) ? tanh_fast(gsum)
                           : fminf(fmaxf(0.2f * gsum + 0.5f, 0.f), 1.f);
      act_s[rb][rg * 16 + rui] = gv;
    }
    __syncthreads();
    if (tid < 64) {
      int b = tid >> 4, ui = tid & 15;
      float i_ = act_s[b][ui];
      float f_ = act_s[b][16 + ui];
      float g_ = act_s[b][32 + ui];
      float o_ = act_s[b][48 + ui];
      float cn = f_ * c_s[b][ui] + i_ * g_;
      c_s[b][ui] = cn;
      float hn = o_ * tanh_fast(cn);
      int gb = bg * GB + b;
      dev_store(&hpg[(size_t)b * U_ + u0 + ui], hn);
      out[((size_t)gb * T_ + t) * U_ + u0 + ui] = hn;
    }
    grp_barrier(slots, w, ++epoch);  // B2: h at coherence point
    {
      float4 hv = load4_coh(hpg + tid * 4);
      *(float4*)&((float*)h_s)[tid * 4] = hv;
    }
    __syncthreads();
  }
}

// ---------------------------------------------------------------------------
extern "C" void kernel_launch(void* const* d_in, const int* in_sizes, int n_in,
                              void* d_out, int out_size, void* d_ws,
                              size_t ws_size, hipStream_t stream) {
  (void)in_sizes;
  (void)n_in;
  (void)out_size;
  (void)ws_size;
  const float* x = (const float*)d_in[0];
  const float* Wk = (const float*)d_in[1];
  const float* Rk = (const float*)d_in[2];
  const float* Ak = (const float*)d_in[3];
  const float* Wa = (const float*)d_in[4];
  const float* Ua = (const float*)d_in[5];
  const float* Va = (const float*)d_in[6];
  const float* bias = (const float*)d_in[7];
  const float* ba = (const float*)d_in[8];
  float* out = (float*)d_out;

  char* ws = (char*)d_ws;
  unsigned short* xk_b = (unsigned short*)(ws);            // 16 MiB
  unsigned short* xA_b = (unsigned short*)(ws + 16777216); // 16 MiB
  float* attxT = (float*)(ws + 33554432);                  // 8 MiB
  float* h_pub = (float*)(ws + 41943040);                  // 64 KiB
  float* sp_g = (float*)(ws + 42008576);                   // 512 KiB
  unsigned* bars = (unsigned*)(ws + 42532864);             // 2 KiB

  gemm_bias_t<1><<<dim3(G_ / 64, (B_ * T_) / 64), 256, 0, stream>>>(
      x, Wk, bias, xk_b, G_);
  gemm_bias_t<1><<<dim3(G_ / 64, (B_ * T_) / 64), 256, 0, stream>>>(
      x, Ak, nullptr, xA_b, G_);
  gemm_bias_t<2><<<dim3(U_ / 64, (B_ * T_) / 64), 256, 0, stream>>>(
      x, Wa, ba, attxT, U_);
  hipMemsetAsync(bars, 0, NGRP * 64 * sizeof(unsigned), stream);

  attlstm_rec<<<dim3(NGRP * WPG), dim3(NT), 0, stream>>>(
      xk_b, xA_b, attxT, Rk, Ua, Va, h_pub, sp_g, bars, out);
}

// Round 9
// 1860.453 us; speedup vs baseline: 3.1878x; 1.0734x over previous
//
#include <hip/hip_runtime.h>
#include <math.h>

#define B_ 32
#define T_ 128
#define D_ 512
#define U_ 512
#define G_ 2048   // 4U
#define NGRP 8    // batch groups
#define GB 4      // batches per group
#define WPG 32    // workgroups per group
#define NT 512    // threads per WG
#define GK 512    // K dim of precompute GEMMs
#define SLOTSTRIDE 16  // slot padding: 64B apart -> no line serialization

__device__ __forceinline__ unsigned short f2bf(float v) {
  unsigned u = __float_as_uint(v);
  return (unsigned short)((u + 0x7FFFu + ((u >> 16) & 1u)) >> 16);
}
__device__ __forceinline__ float bf2f(unsigned short u) {
  return __uint_as_float(((unsigned)u) << 16);
}

// 4B cache-bypassing store (write-through to the device coherence point).
__device__ __forceinline__ void dev_store(float* p, float v) {
  __hip_atomic_store(p, v, __ATOMIC_RELAXED, __HIP_MEMORY_SCOPE_AGENT);
}

// 32 contiguous floats as 8 pipelined dwordx4 bypass loads + ONE waitcnt.
__device__ __forceinline__ void gather32(const float* p, float4& a0, float4& a1,
                                         float4& a2, float4& a3, float4& a4,
                                         float4& a5, float4& a6, float4& a7) {
  asm volatile(
      "global_load_dwordx4 %0, %8, off sc0 sc1\n\t"
      "global_load_dwordx4 %1, %8, off offset:16 sc0 sc1\n\t"
      "global_load_dwordx4 %2, %8, off offset:32 sc0 sc1\n\t"
      "global_load_dwordx4 %3, %8, off offset:48 sc0 sc1\n\t"
      "global_load_dwordx4 %4, %8, off offset:64 sc0 sc1\n\t"
      "global_load_dwordx4 %5, %8, off offset:80 sc0 sc1\n\t"
      "global_load_dwordx4 %6, %8, off offset:96 sc0 sc1\n\t"
      "global_load_dwordx4 %7, %8, off offset:112 sc0 sc1\n\t"
      "s_waitcnt vmcnt(0)"
      : "=&v"(a0), "=&v"(a1), "=&v"(a2), "=&v"(a3), "=&v"(a4), "=&v"(a5),
        "=&v"(a6), "=&v"(a7)
      : "v"(p)
      : "memory");
}

__device__ __forceinline__ float4 load4_coh(const float* p) {
  float4 r;
  asm volatile(
      "global_load_dwordx4 %0, %1, off sc0 sc1\n\t"
      "s_waitcnt vmcnt(0)"
      : "=&v"(r)
      : "v"(p)
      : "memory");
  return r;
}

// 16B bypass publish as 4 relaxed-atomic scalar stores (LLVM inline-asm can't
// take float4 inputs; compiler emits 4 back-to-back bypassing stores, drained
// by grp_arrive's __syncthreads vmcnt(0)).
__device__ __forceinline__ void store4_coh(float* p, float4 v) {
  dev_store(p + 0, v.x);
  dev_store(p + 1, v.y);
  dev_store(p + 2, v.z);
  dev_store(p + 3, v.w);
}

// ---------------------------------------------------------------------------
// Precompute GEMM: C[M,N] = A[M,512] @ W[512,N] + bias  (bias may be null)
// MODE 1: bf16 row-major; MODE 2: fp32 (B,U,T)-transposed
// ---------------------------------------------------------------------------
template <int MODE>
__global__ __launch_bounds__(256) void gemm_bias_t(const float* __restrict__ A,
                                                   const float* __restrict__ W,
                                                   const float* __restrict__ bias,
                                                   void* __restrict__ Cout, int N) {
  __shared__ float As[16][68];
  __shared__ float Ws[16][64];
  const int tid = threadIdx.x;
  const int rowbase = blockIdx.y * 64;
  const int colbase = blockIdx.x * 64;
  const int ty = tid >> 4, tx = tid & 15;
  const int ar = tid >> 2, ak = (tid & 3) << 2;
  const int wk = tid >> 4, wc = (tid & 15) << 2;
  float acc[4][4] = {{0.f, 0.f, 0.f, 0.f}};
  for (int k0 = 0; k0 < GK; k0 += 16) {
    float4 av = *(const float4*)(A + (size_t)(rowbase + ar) * GK + k0 + ak);
    float4 wv = *(const float4*)(W + (size_t)(k0 + wk) * N + colbase + wc);
    __syncthreads();
    As[ak + 0][ar] = av.x;
    As[ak + 1][ar] = av.y;
    As[ak + 2][ar] = av.z;
    As[ak + 3][ar] = av.w;
    *(float4*)(&Ws[wk][wc]) = wv;
    __syncthreads();
#pragma unroll
    for (int kk = 0; kk < 16; ++kk) {
      float4 a = *(const float4*)(&As[kk][ty << 2]);
      float4 wv2 = *(const float4*)(&Ws[kk][tx << 2]);
      float a4[4] = {a.x, a.y, a.z, a.w};
      float w4[4] = {wv2.x, wv2.y, wv2.z, wv2.w};
#pragma unroll
      for (int i = 0; i < 4; ++i)
#pragma unroll
        for (int jj = 0; jj < 4; ++jj) acc[i][jj] += a4[i] * w4[jj];
    }
  }
  float4 bv = bias ? *(const float4*)(bias + colbase + (tx << 2))
                   : make_float4(0.f, 0.f, 0.f, 0.f);
#pragma unroll
  for (int i = 0; i < 4; ++i) {
    const int row = rowbase + (ty << 2) + i;
    float o[4] = {acc[i][0] + bv.x, acc[i][1] + bv.y, acc[i][2] + bv.z,
                  acc[i][3] + bv.w};
    if (MODE == 1) {
      ushort4 ob;
      ob.x = f2bf(o[0]); ob.y = f2bf(o[1]); ob.z = f2bf(o[2]); ob.w = f2bf(o[3]);
      *(ushort4*)((unsigned short*)Cout + (size_t)row * N + colbase + (tx << 2)) = ob;
    } else {
      const int b = row >> 7, tt = row & 127;
#pragma unroll
      for (int jj = 0; jj < 4; ++jj) {
        int u = colbase + (tx << 2) + jj;
        ((float*)Cout)[((size_t)b * U_ + u) * T_ + tt] = o[jj];
      }
    }
  }
}

__device__ __forceinline__ float tanh_fast(float x) {
  return 1.f - 2.f / (__expf(2.f * x) + 1.f);
}

// Split-phase RMW-free barrier. Arrive: own padded slot store (own line).
// Wait: one 32-line parallel vector poll + ballot. Independent work goes
// between arrive and wait.
__device__ __forceinline__ void grp_arrive(unsigned* slots, int w,
                                           unsigned epoch) {
  __syncthreads();  // drains vmcnt(0): all bypass stores at coherence point
  if (threadIdx.x == 0)
    __hip_atomic_store(&slots[w * SLOTSTRIDE], epoch, __ATOMIC_RELAXED,
                       __HIP_MEMORY_SCOPE_AGENT);
}
__device__ __forceinline__ void grp_wait(const unsigned* slots, unsigned epoch) {
  if (threadIdx.x < 64) {
    bool done = false;
    do {
      unsigned v = (threadIdx.x < WPG)
                       ? __hip_atomic_load(&slots[threadIdx.x * SLOTSTRIDE],
                                           __ATOMIC_RELAXED,
                                           __HIP_MEMORY_SCOPE_AGENT)
                       : epoch;
      done = __all(v >= epoch);
    } while (!done);
  }
  __syncthreads();
}

// ---------------------------------------------------------------------------
// Weight-stationary recurrence, split-phase barriers. 8 groups x 32 WGs x
// 512 threads. B1 wait hidden under the h@Rk matvec; B2 wait hides the xk
// prefetch. sp layout (b,t,w): reader's 32 partials = one 128B block.
// ---------------------------------------------------------------------------
__global__ __launch_bounds__(NT) void attlstm_rec(
    const unsigned short* __restrict__ xk,  // (B,T,4U) bf16
    const unsigned short* __restrict__ xA,  // (B,T,4U) bf16
    const float* __restrict__ attxT,        // (B,U,T) fp32
    const float* __restrict__ Rk,           // (U,4U)
    const float* __restrict__ Um,           // (U,U)
    const float* __restrict__ V,            // (U)
    float* __restrict__ h_pub,              // (NGRP,GB,U)
    float* __restrict__ sp_g,               // (NGRP,GB,T,WPG)
    unsigned* __restrict__ bars,            // (NGRP,WPG*SLOTSTRIDE)
    float* __restrict__ out) {              // (B,T,U)
  const int bg = blockIdx.x & 7;
  const int w = blockIdx.x >> 3;
  const int tid = threadIdx.x;
  const int u0 = w * 16;
  const int tk = tid >> 4;  // 0..31 (K-chunk of 16)
  const int tc = tid & 15;  // col-quad id
  const int gcol = (tc >> 2) * U_ + u0 + (tc & 3) * 4;
  const int wv = tid >> 6;
  const int lane = tid & 63;
  const int bS = tid >> 7;
  const int tS = tid & 127;
  const int rb = tid >> 6;  // reducer role (tid<256)
  const int rc = tid & 63;
  const int rtc = rc >> 2, rcomp = rc & 3;
  const int rg = rtc >> 2;
  const int rui = ((rtc & 3) << 2) | rcomp;
  const int rcol = rg * U_ + u0 + rui;

  __shared__ float attx_l[16 * GB * T_];  // 32 KB
  __shared__ float h_s[GB][U_];           // 8 KB
  __shared__ float4 red2[8][GB][17];
  __shared__ float hUred[8][GB][17];
  __shared__ float sc_s[GB][T_];
  __shared__ float hU_s[GB][16];
  __shared__ float act_s[GB][64];
  __shared__ float c_s[GB][16];
  __shared__ float lsum_s[8];
  __shared__ float Vs_l[16];

  float4 Rw[16];
  float Uw[16];
#pragma unroll
  for (int i = 0; i < 16; ++i)
    Rw[i] = *(const float4*)(Rk + (size_t)(tk * 16 + i) * G_ + gcol);
#pragma unroll
  for (int i = 0; i < 16; ++i)
    Uw[i] = Um[(size_t)(tk * 16 + i) * U_ + u0 + tc];

  for (int idx = tid; idx < 16 * GB * T_; idx += NT) {
    int uc = idx >> 9;
    int b = (idx >> 7) & 3;
    int tt = idx & 127;
    attx_l[idx] = attxT[((size_t)(bg * GB + b) * U_ + u0 + uc) * T_ + tt];
  }
  for (int i = tid; i < GB * U_; i += NT) ((float*)h_s)[i] = 0.f;
  if (tid < GB * 16) ((float*)c_s)[tid] = 0.f;
  if (tid < 16) Vs_l[tid] = V[u0 + tid];
  unsigned* slots = bars + bg * (WPG * SLOTSTRIDE);
  unsigned epoch = 0;
  float* hpg = h_pub + (size_t)bg * GB * U_;
  float* spg = sp_g + (size_t)bg * GB * T_ * WPG;
  float xkv = 0.f;
  if (tid < 256) xkv = bf2f(xk[((size_t)(bg * GB + rb) * T_ + 0) * G_ + rcol]);
  __syncthreads();

  for (int t = 0; t < T_; ++t) {
    // ===== P1a: hU partial (h@Um own u-slice) -> scores -> sp publish
    float hUa[GB];
#pragma unroll
    for (int b = 0; b < GB; ++b) {
      float hu = 0.f;
      const float* hp = &h_s[b][tk * 16];
#pragma unroll
      for (int i = 0; i < 16; ++i) hu += hp[i] * Uw[i];
      hUa[b] = hu;
    }
#pragma unroll
    for (int b = 0; b < GB; ++b) {
      float hu = hUa[b];
      hu += __shfl_down(hu, 32);
      hu += __shfl_down(hu, 16);
      if (lane < 16) hUred[wv][b][lane] = hu;
    }
    __syncthreads();
    if (tid < 64) {
      int b = tid >> 4, u = tid & 15;
      float s = 0.f;
#pragma unroll
      for (int k = 0; k < 8; ++k) s += hUred[k][b][u];
      hU_s[b][u] = s;
    }
    __syncthreads();
    {  // score partials over own 16-u slice, all (b,t'); layout (b,t',w)
      float s = 0.f;
      const float* ax = &attx_l[bS * T_ + tS];
#pragma unroll
      for (int uc = 0; uc < 16; ++uc) {
        float e = tanh_fast(ax[uc * (GB * T_)] + hU_s[bS][uc]);
        s += e * Vs_l[uc];
      }
      dev_store(&spg[((size_t)bS * T_ + tS) * WPG + w], s);
    }
    grp_arrive(slots, w, ++epoch);  // B1 arrive

    // ===== B1 shadow: the big h@Rk matvec (independent of sp)
    float4 accR[GB];
#pragma unroll
    for (int b = 0; b < GB; ++b) {
      float4 a = make_float4(0.f, 0.f, 0.f, 0.f);
      const float* hp = &h_s[b][tk * 16];
#pragma unroll
      for (int i = 0; i < 16; ++i) {
        float hv = hp[i];
        a.x += hv * Rw[i].x;
        a.y += hv * Rw[i].y;
        a.z += hv * Rw[i].z;
        a.w += hv * Rw[i].w;
      }
      accR[b] = a;
    }
    grp_wait(slots, epoch);  // B1 wait

    // ===== P2: wide bypass gather -> softmax (no max pass) -> fold -> LSTM
    {
      const float* spp = spg + ((size_t)bS * T_ + tS) * WPG;
      float4 a0, a1, a2, a3, a4, a5, a6, a7;
      gather32(spp, a0, a1, a2, a3, a4, a5, a6, a7);
      float s = (((a0.x + a0.y) + (a0.z + a0.w)) + ((a1.x + a1.y) + (a1.z + a1.w))) +
                (((a2.x + a2.y) + (a2.z + a2.w)) + ((a3.x + a3.y) + (a3.z + a3.w))) +
                (((a4.x + a4.y) + (a4.z + a4.w)) + ((a5.x + a5.y) + (a5.z + a5.w))) +
                (((a6.x + a6.y) + (a6.z + a6.w)) + ((a7.x + a7.y) + (a7.z + a7.w)));
      float e = __expf(s);  // |s| <= ||V||_1 ~ 20: fp32-safe without shift
      sc_s[bS][tS] = e;
      float ls = e;  // lanes of this wave share bS
      for (int o = 32; o > 0; o >>= 1) ls += __shfl_down(ls, o);
      if (lane == 0) lsum_s[wv] = ls;
    }
    __syncthreads();
#pragma unroll
    for (int b = 0; b < GB; ++b) {
      const unsigned short* xap =
          xA + ((size_t)(bg * GB + b) * T_ + tk * 4) * G_ + gcol;
      float4 az = make_float4(0.f, 0.f, 0.f, 0.f);
#pragma unroll
      for (int i = 0; i < 4; ++i) {
        ushort4 xv = *(const ushort4*)(xap + (size_t)i * G_);
        float al = sc_s[b][tk * 4 + i];
        az.x += al * bf2f(xv.x);
        az.y += al * bf2f(xv.y);
        az.z += al * bf2f(xv.z);
        az.w += al * bf2f(xv.w);
      }
      float il = 1.f / (lsum_s[2 * b] + lsum_s[2 * b + 1]);
      float4 comb;
      comb.x = accR[b].x + il * az.x;
      comb.y = accR[b].y + il * az.y;
      comb.z = accR[b].z + il * az.z;
      comb.w = accR[b].w + il * az.w;
      comb.x += __shfl_down(comb.x, 32);
      comb.y += __shfl_down(comb.y, 32);
      comb.z += __shfl_down(comb.z, 32);
      comb.w += __shfl_down(comb.w, 32);
      comb.x += __shfl_down(comb.x, 16);
      comb.y += __shfl_down(comb.y, 16);
      comb.z += __shfl_down(comb.z, 16);
      comb.w += __shfl_down(comb.w, 16);
      if (lane < 16) red2[wv][b][lane] = comb;
    }
    __syncthreads();
    if (tid < 256) {
      float gsum = xkv;
      const float* r2 = (const float*)red2;
#pragma unroll
      for (int k = 0; k < 8; ++k)
        gsum += r2[(((size_t)(k * GB + rb) * 17) + rtc) * 4 + rcomp];
      float gv = (rg == 2) ? tanh_fast(gsum)
                           : fminf(fmaxf(0.2f * gsum + 0.5f, 0.f), 1.f);
      act_s[rb][rg * 16 + rui] = gv;
    }
    __syncthreads();
    if (tid < 16) {
      int b = tid >> 2, uq = tid & 3;
      float4 hn4;
#pragma unroll
      for (int k2 = 0; k2 < 4; ++k2) {
        int ui = uq * 4 + k2;
        float i_ = act_s[b][ui];
        float f_ = act_s[b][16 + ui];
        float g_ = act_s[b][32 + ui];
        float o_ = act_s[b][48 + ui];
        float cn = f_ * c_s[b][ui] + i_ * g_;
        c_s[b][ui] = cn;
        ((float*)&hn4)[k2] = o_ * tanh_fast(cn);
      }
      int gb = bg * GB + b;
      store4_coh(&hpg[(size_t)b * U_ + u0 + uq * 4], hn4);
      *(float4*)(out + ((size_t)gb * T_ + t) * U_ + u0 + uq * 4) = hn4;
    }
    grp_arrive(slots, w, ++epoch);  // B2 arrive

    // ===== B2 shadow: prefetch next step's xk
    int tn = (t + 1 < T_) ? t + 1 : t;
    float xkv_n = 0.f;
    if (tid < 256)
      xkv_n = bf2f(xk[((size_t)(bg * GB + rb) * T_ + tn) * G_ + rcol]);
    grp_wait(slots, epoch);  // B2 wait

    {
      float4 hv = load4_coh(hpg + tid * 4);
      *(float4*)&((float*)h_s)[tid * 4] = hv;
    }
    xkv = xkv_n;
    __syncthreads();
  }
}

// ---------------------------------------------------------------------------
extern "C" void kernel_launch(void* const* d_in, const int* in_sizes, int n_in,
                              void* d_out, int out_size, void* d_ws,
                              size_t ws_size, hipStream_t stream) {
  (void)in_sizes;
  (void)n_in;
  (void)out_size;
  (void)ws_size;
  const float* x = (const float*)d_in[0];
  const float* Wk = (const float*)d_in[1];
  const float* Rk = (const float*)d_in[2];
  const float* Ak = (const float*)d_in[3];
  const float* Wa = (const float*)d_in[4];
  const float* Ua = (const float*)d_in[5];
  const float* Va = (const float*)d_in[6];
  const float* bias = (const float*)d_in[7];
  const float* ba = (const float*)d_in[8];
  float* out = (float*)d_out;

  char* ws = (char*)d_ws;
  unsigned short* xk_b = (unsigned short*)(ws);            // 16 MiB
  unsigned short* xA_b = (unsigned short*)(ws + 16777216); // 16 MiB
  float* attxT = (float*)(ws + 33554432);                  // 8 MiB
  float* h_pub = (float*)(ws + 41943040);                  // 64 KiB
  float* sp_g = (float*)(ws + 42008576);                   // 512 KiB
  unsigned* bars = (unsigned*)(ws + 42532864);             // 16 KiB

  gemm_bias_t<1><<<dim3(G_ / 64, (B_ * T_) / 64), 256, 0, stream>>>(
      x, Wk, bias, xk_b, G_);
  gemm_bias_t<1><<<dim3(G_ / 64, (B_ * T_) / 64), 256, 0, stream>>>(
      x, Ak, nullptr, xA_b, G_);
  gemm_bias_t<2><<<dim3(U_ / 64, (B_ * T_) / 64), 256, 0, stream>>>(
      x, Wa, ba, attxT, U_);
  (void)hipMemsetAsync(bars, 0, NGRP * WPG * SLOTSTRIDE * sizeof(unsigned),
                       stream);

  attlstm_rec<<<dim3(NGRP * WPG), dim3(NT), 0, stream>>>(
      xk_b, xA_b, attxT, Rk, Ua, Va, h_pub, sp_g, bars, out);
}